// Round 14
// baseline (213.357 us; speedup 1.0000x reference)
//
#include <hip/hip_runtime.h>

constexpr int D = 128;
constexpr int H = 256;
constexpr float EPS = 1e-5f;

typedef __attribute__((ext_vector_type(8))) __bf16  bf16x8;   // 4 VGPRs
typedef __attribute__((ext_vector_type(4))) float   f32x4;

static __device__ __forceinline__ unsigned short f2bfu(float f) {
    unsigned u = __float_as_uint(f);
    return (unsigned short)((u + 0x7FFFu + ((u >> 16) & 1u)) >> 16);   // RNE
}
static __device__ __forceinline__ float bf2f(unsigned short u) {
    return __uint_as_float((unsigned)u << 16);
}

static __device__ __forceinline__ f32x4 mfma16x16x32(bf16x8 a, bf16x8 b, f32x4 c) {
    return __builtin_amdgcn_mfma_f32_16x16x32_bf16(a, b, c, 0, 0, 0);
}

// ---------------------------------------------------------------------------
// Pack W element e (bf16 MFMA B-fragment order) — device helper.
// ---------------------------------------------------------------------------
static __device__ __forceinline__ void pack_w_elem(
    const float* __restrict__ W, unsigned short* __restrict__ Wp, int K, int Ncols, int e)
{
    int i  = e & 7;
    int l  = (e >> 3) & 63;
    int jt = e >> 9;
    int nt = K >> 5;
    int j  = jt / nt;
    int t  = jt - j * nt;
    int k  = 32 * t + ((l >> 4) << 3) + i;
    int c  = 16 * j + (l & 15);
    Wp[e] = f2bfu(W[(size_t)k * Ncols + c]);
}

// ---------------------------------------------------------------------------
// prep: pack W1 [0,128), pack W2 [128,256), zero counts [256,256+zb),
// zero cnt0 [256+zb, 256+2zb)
// ---------------------------------------------------------------------------
__global__ __launch_bounds__(256) void prep_kernel(
    const float* __restrict__ W1, unsigned short* __restrict__ W1p,
    const float* __restrict__ W2, unsigned short* __restrict__ W2p,
    int* __restrict__ counts, int* __restrict__ cnt0, int N, int zeroBlocks)
{
    int b = blockIdx.x;
    if (b < 128) {
        pack_w_elem(W1, W1p, D, H, b * 256 + threadIdx.x);
    } else if (b < 256) {
        pack_w_elem(W2, W2p, H, D, (b - 128) * 256 + threadIdx.x);
    } else if (b < 256 + zeroBlocks) {
        int i = (b - 256) * 256 + threadIdx.x;
        if (i < N) counts[i] = 0;
    } else {
        int i = (b - 256 - zeroBlocks) * 256 + threadIdx.x;
        if (i < N) cnt0[i] = 0;
    }
}

// ---------------------------------------------------------------------------
// Fused conv + hist (R13-verified): 64 rows/block, 4 waves x 16 rows,
// LDS-staged double-buffered weights, coalesced convb epilogue via Hs.
// ---------------------------------------------------------------------------
__global__ __launch_bounds__(256) void conv_hist_kernel(
    const float* __restrict__ x,
    const unsigned short* __restrict__ W1p, const float* __restrict__ b1,
    const float* __restrict__ g1, const float* __restrict__ be1,
    const unsigned short* __restrict__ W2p, const float* __restrict__ b2,
    const float* __restrict__ g2, const float* __restrict__ be2,
    unsigned short* __restrict__ convb, int N,
    const int* __restrict__ eidx, int* __restrict__ counts, int E, int convBlocks)
{
    __shared__ unsigned short Hs[64 * 256];   // 32 KB
    __shared__ unsigned short Ws[2][8192];    // 2 x 16 KB weight staging

    if ((int)blockIdx.x >= convBlocks) {
        int e = (blockIdx.x - convBlocks) * 256 + threadIdx.x;
        if (e < E) atomicAdd(&counts[eidx[e]], 1);
        return;
    }

    const int wv   = threadIdx.x >> 6;
    const int lane = threadIdx.x & 63;
    const int rrow = lane & 15;
    const int kgrp = lane >> 4;
    const int r0   = blockIdx.x * 64 + wv * 16;

    float4 sv0, sv1, sv2, sv3;
    auto issueW = [&](const unsigned short* Wp, int c) {
        const float4* s = (const float4*)(Wp + c * 8192);
        sv0 = s[threadIdx.x];
        sv1 = s[threadIdx.x + 256];
        sv2 = s[threadIdx.x + 512];
        sv3 = s[threadIdx.x + 768];
    };
    auto writeS = [&](int b) {
        float4* d = (float4*)Ws[b];
        d[threadIdx.x]       = sv0;
        d[threadIdx.x + 256] = sv1;
        d[threadIdx.x + 512] = sv2;
        d[threadIdx.x + 768] = sv3;
    };

    int arow = r0 + rrow; if (arow >= N) arow = N - 1;
    const float* xr = x + (size_t)arow * D + kgrp * 8;
    bf16x8 A1[4];
    #pragma unroll
    for (int t = 0; t < 4; ++t) {
        float4 fa = *(const float4*)(xr + t * 32);
        float4 fb = *(const float4*)(xr + t * 32 + 4);
        bf16x8 a;
        a[0] = (__bf16)fa.x; a[1] = (__bf16)fa.y; a[2] = (__bf16)fa.z; a[3] = (__bf16)fa.w;
        a[4] = (__bf16)fb.x; a[5] = (__bf16)fb.y; a[6] = (__bf16)fb.z; a[7] = (__bf16)fb.w;
        A1[t] = a;
    }

    f32x4 acc[16];
    #pragma unroll
    for (int j = 0; j < 16; ++j) acc[j] = (f32x4){0.f, 0.f, 0.f, 0.f};

    issueW(W1p, 0); writeS(0); __syncthreads();
    #pragma unroll
    for (int c = 0; c < 4; ++c) {
        if (c < 3) issueW(W1p, c + 1);
        #pragma unroll
        for (int jj = 0; jj < 4; ++jj) {
            #pragma unroll
            for (int t = 0; t < 4; ++t) {
                bf16x8 B = *(const bf16x8*)((const char*)Ws[c & 1]
                             + ((jj * 4 + t) * 512 + lane * 8) * 2);
                acc[c * 4 + jj] = mfma16x16x32(A1[t], B, acc[c * 4 + jj]);
            }
        }
        if (c < 3) writeS((c + 1) & 1);
        __syncthreads();
    }

    float b1r[16], g1r[16], be1r[16];
    #pragma unroll
    for (int j = 0; j < 16; ++j) {
        int c = 16 * j + rrow;
        b1r[j] = b1[c]; g1r[j] = g1[c]; be1r[j] = be1[c];
    }

    float s1[4] = {0,0,0,0}, s2[4] = {0,0,0,0};
    #pragma unroll
    for (int j = 0; j < 16; ++j) {
        #pragma unroll
        for (int r = 0; r < 4; ++r) {
            float v = acc[j][r] + b1r[j];
            acc[j][r] = v;
            s1[r] += v; s2[r] += v * v;
        }
    }
    #pragma unroll
    for (int m = 1; m < 16; m <<= 1) {
        #pragma unroll
        for (int r = 0; r < 4; ++r) {
            s1[r] += __shfl_xor(s1[r], m);
            s2[r] += __shfl_xor(s2[r], m);
        }
    }

    issueW(W2p, 0);   // overlap W2 chunk-0 loads with LN1/Hs work

    #pragma unroll
    for (int r = 0; r < 4; ++r) {
        float mu  = s1[r] * (1.f / H);
        float var = s2[r] * (1.f / H) - mu * mu;
        float rs  = rsqrtf(var + EPS);
        int row = wv * 16 + kgrp * 4 + r;
        #pragma unroll
        for (int j = 0; j < 16; ++j) {
            float h = fmaxf((acc[j][r] - mu) * rs * g1r[j] + be1r[j], 0.f);
            int byte = (row << 9) + ((16 * j + rrow) << 1);
            byte ^= (row & 15) << 4;
            *(unsigned short*)((char*)Hs + byte) = f2bfu(h);
        }
    }

    bf16x8 A2[8];
    #pragma unroll
    for (int t = 0; t < 8; ++t) {
        int row  = wv * 16 + rrow;
        int byte = (row << 9) + ((t * 32 + kgrp * 8) << 1);
        byte ^= (row & 15) << 4;
        A2[t] = *(const bf16x8*)((const char*)Hs + byte);
    }

    writeS(0); __syncthreads();

    f32x4 acc2[8];
    #pragma unroll
    for (int j = 0; j < 8; ++j) acc2[j] = (f32x4){0.f, 0.f, 0.f, 0.f};
    #pragma unroll
    for (int c = 0; c < 4; ++c) {
        if (c < 3) issueW(W2p, c + 1);
        #pragma unroll
        for (int jj = 0; jj < 2; ++jj) {
            #pragma unroll
            for (int t = 0; t < 8; ++t) {
                bf16x8 B = *(const bf16x8*)((const char*)Ws[c & 1]
                             + ((jj * 8 + t) * 512 + lane * 8) * 2);
                acc2[c * 2 + jj] = mfma16x16x32(A2[t], B, acc2[c * 2 + jj]);
            }
        }
        if (c < 3) writeS((c + 1) & 1);
        __syncthreads();
    }

    float b2r[8], g2r[8], be2r[8];
    #pragma unroll
    for (int j = 0; j < 8; ++j) {
        int c = 16 * j + rrow;
        b2r[j] = b2[c]; g2r[j] = g2[c]; be2r[j] = be2[c];
    }

    float u1[4] = {0,0,0,0}, u2[4] = {0,0,0,0};
    #pragma unroll
    for (int j = 0; j < 8; ++j) {
        #pragma unroll
        for (int r = 0; r < 4; ++r) {
            float v = acc2[j][r] + b2r[j];
            acc2[j][r] = v;
            u1[r] += v; u2[r] += v * v;
        }
    }
    #pragma unroll
    for (int m = 1; m < 16; m <<= 1) {
        #pragma unroll
        for (int r = 0; r < 4; ++r) {
            u1[r] += __shfl_xor(u1[r], m);
            u2[r] += __shfl_xor(u2[r], m);
        }
    }

    #pragma unroll
    for (int r = 0; r < 4; ++r) {
        float mu  = u1[r] * (1.f / D);
        float var = u2[r] * (1.f / D) - mu * mu;
        float rs  = rsqrtf(var + EPS);
        int row = wv * 16 + kgrp * 4 + r;
        #pragma unroll
        for (int j = 0; j < 8; ++j) {
            float o = (acc2[j][r] - mu) * rs * g2r[j] + be2r[j];
            int byte = (row << 9) + ((16 * j + rrow) << 1);
            byte ^= (row & 15) << 4;
            *(unsigned short*)((char*)Hs + byte) = f2bfu(o);
        }
    }

    // coalesced store: per k, each 4-lane group writes a dense 64B segment
    {
        int lrow = wv * 16 + (lane >> 2);
        int grow = r0 + (lane >> 2);
        if (grow < N) {
            #pragma unroll
            for (int k = 0; k < 4; ++k) {
                int chunk = k * 4 + (lane & 3);
                int byte  = (lrow << 9) + (chunk << 4);
                byte ^= (lrow & 15) << 4;
                uint4 v = *(const uint4*)((const char*)Hs + byte);
                *(uint4*)(convb + (size_t)grow * D + chunk * 8) = v;
            }
        }
    }
}

// ---------------------------------------------------------------------------
// scan1: per-1024-block exclusive partials -> row_part, block totals -> bsums
// scan2: exclusive scan of bsums in place.  (scan3 folded into consumers)
// ---------------------------------------------------------------------------
__global__ __launch_bounds__(256) void scan1_kernel(
    const int* __restrict__ counts, int* __restrict__ row_part,
    int* __restrict__ bsums, int N)
{
    __shared__ int sd[256];
    int t  = threadIdx.x;
    int i0 = blockIdx.x * 1024 + t * 4;
    int c0 = (i0+0 < N) ? counts[i0+0] : 0;
    int c1 = (i0+1 < N) ? counts[i0+1] : 0;
    int c2 = (i0+2 < N) ? counts[i0+2] : 0;
    int c3 = (i0+3 < N) ? counts[i0+3] : 0;
    int s  = c0 + c1 + c2 + c3;
    sd[t] = s;
    __syncthreads();
    #pragma unroll
    for (int off = 1; off < 256; off <<= 1) {
        int v = (t >= off) ? sd[t - off] : 0;
        __syncthreads();
        sd[t] += v;
        __syncthreads();
    }
    int ex = sd[t] - s;
    if (i0+0 < N) row_part[i0+0] = ex;
    if (i0+1 < N) row_part[i0+1] = ex + c0;
    if (i0+2 < N) row_part[i0+2] = ex + c0 + c1;
    if (i0+3 < N) row_part[i0+3] = ex + c0 + c1 + c2;
    if (t == 255) bsums[blockIdx.x] = sd[255];
}

__global__ __launch_bounds__(128) void scan2_kernel(int* __restrict__ bsums, int NB)
{
    __shared__ int sd[128];
    int t = threadIdx.x;
    int v = (t < NB) ? bsums[t] : 0;
    sd[t] = v;
    __syncthreads();
    #pragma unroll
    for (int off = 1; off < 128; off <<= 1) {
        int u = (t >= off) ? sd[t - off] : 0;
        __syncthreads();
        sd[t] += u;
        __syncthreads();
    }
    if (t < NB) bsums[t] = sd[t] - v;
}

// ---------------------------------------------------------------------------
// fill: p = row_part[src] + bsums[src>>10] + cnt0[src]++  ;  edat[p]={e,dst}
// ---------------------------------------------------------------------------
__global__ __launch_bounds__(256) void fill_kernel(
    const int* __restrict__ eidx,
    const int* __restrict__ row_part, const int* __restrict__ bsums,
    int* __restrict__ cnt0, int2* __restrict__ edat, int E)
{
    int e = blockIdx.x * blockDim.x + threadIdx.x;
    if (e < E) {
        int s    = eidx[e];
        int base = row_part[s] + bsums[s >> 10];
        int p    = base + atomicAdd(&cnt0[s], 1);
        edat[p]  = make_int2(e, eidx[E + e]);
    }
}

// ---------------------------------------------------------------------------
// out[v] = LN( x[v] + sum_{e: src=v} conv_bf16[dst]*eattr[e] )
// Segment bounds computed on the fly from row_part + bsums (scan3 folded in).
// ---------------------------------------------------------------------------
__global__ __launch_bounds__(256) void gather_ln_kernel(
    const float* __restrict__ x, const unsigned short* __restrict__ convb,
    const float* __restrict__ eattr,
    const int* __restrict__ row_part, const int* __restrict__ bsums,
    const int2* __restrict__ edat,
    const float* __restrict__ g, const float* __restrict__ b,
    float* __restrict__ out, int N, int E)
{
    int node = blockIdx.x * 4 + (threadIdx.x >> 6);
    if (node >= N) return;
    int lane = threadIdx.x & 63;
    int half = lane >> 5;
    int c4   = (lane & 31) * 4;

    int jb = row_part[node] + bsums[node >> 10];
    int je = (node + 1 < N) ? (row_part[node + 1] + bsums[(node + 1) >> 10]) : E;

    // issue x load early so it overlaps the edge stream (consumed after loop)
    float4 xv = make_float4(0.f, 0.f, 0.f, 0.f);
    if (half == 0) xv = *(const float4*)(x + (size_t)node * D + c4);

    float4 acc = make_float4(0.f, 0.f, 0.f, 0.f);
    int j = jb + half;

    for (; j + 2 < je; j += 4) {
        int2 ea = edat[j];
        int2 eb = edat[j + 2];
        ushort4 ca = *(const ushort4*)(convb + (size_t)ea.y * D + c4);
        float4  aa = *(const float4*) (eattr + (size_t)ea.x * D + c4);
        ushort4 cb = *(const ushort4*)(convb + (size_t)eb.y * D + c4);
        float4  ab = *(const float4*) (eattr + (size_t)eb.x * D + c4);
        acc.x += bf2f(ca.x) * aa.x; acc.y += bf2f(ca.y) * aa.y;
        acc.z += bf2f(ca.z) * aa.z; acc.w += bf2f(ca.w) * aa.w;
        acc.x += bf2f(cb.x) * ab.x; acc.y += bf2f(cb.y) * ab.y;
        acc.z += bf2f(cb.z) * ab.z; acc.w += bf2f(cb.w) * ab.w;
    }
    if (j < je) {
        int2 ea = edat[j];
        ushort4 ca = *(const ushort4*)(convb + (size_t)ea.y * D + c4);
        float4  aa = *(const float4*) (eattr + (size_t)ea.x * D + c4);
        acc.x += bf2f(ca.x) * aa.x; acc.y += bf2f(ca.y) * aa.y;
        acc.z += bf2f(ca.z) * aa.z; acc.w += bf2f(ca.w) * aa.w;
    }

    acc.x += xv.x; acc.y += xv.y; acc.z += xv.z; acc.w += xv.w;

    acc.x += __shfl_xor(acc.x, 32);
    acc.y += __shfl_xor(acc.y, 32);
    acc.z += __shfl_xor(acc.z, 32);
    acc.w += __shfl_xor(acc.w, 32);

    float s1 = acc.x + acc.y + acc.z + acc.w;
    float s2 = acc.x*acc.x + acc.y*acc.y + acc.z*acc.z + acc.w*acc.w;
    #pragma unroll
    for (int o = 1; o < 32; o <<= 1) {
        s1 += __shfl_xor(s1, o);
        s2 += __shfl_xor(s2, o);
    }
    float mu  = s1 * (1.f / D);
    float var = s2 * (1.f / D) - mu * mu;
    float rs  = rsqrtf(var + EPS);
    if (half == 0) {
        float4 gv = *(const float4*)(g + c4);
        float4 bv = *(const float4*)(b + c4);
        float4 o4;
        o4.x = (acc.x - mu) * rs * gv.x + bv.x;
        o4.y = (acc.y - mu) * rs * gv.y + bv.y;
        o4.z = (acc.z - mu) * rs * gv.z + bv.z;
        o4.w = (acc.w - mu) * rs * gv.w + bv.w;
        *(float4*)(out + (size_t)node * D + c4) = o4;
    }
}

extern "C" void kernel_launch(void* const* d_in, const int* in_sizes, int n_in,
                              void* d_out, int out_size, void* d_ws, size_t ws_size,
                              hipStream_t stream) {
    const float* x     = (const float*)d_in[0];
    const int*   eidx  = (const int*)  d_in[1];
    const float* eattr = (const float*)d_in[2];
    const float* W1    = (const float*)d_in[3];
    const float* b1    = (const float*)d_in[4];
    const float* g1    = (const float*)d_in[5];
    const float* be1   = (const float*)d_in[6];
    const float* W2    = (const float*)d_in[7];
    const float* b2    = (const float*)d_in[8];
    const float* g2    = (const float*)d_in[9];
    const float* be2   = (const float*)d_in[10];
    const float* g_out = (const float*)d_in[11];
    const float* b_out = (const float*)d_in[12];

    const int N = in_sizes[0] / D;   // 100000
    const int E = in_sizes[1] / 2;   // 640000

    float* out = (float*)d_out;

    // workspace layout (256B aligned)
    auto align_up = [](size_t v) { return (v + 255) & ~(size_t)255; };
    size_t convB = align_up((size_t)N * D * sizeof(unsigned short));  // 25.6 MB
    size_t cntB  = align_up((size_t)N * sizeof(int));
    size_t rsB   = align_up((size_t)N * sizeof(int));
    size_t c0B   = align_up((size_t)N * sizeof(int));
    size_t bsB   = align_up(128 * sizeof(int));
    size_t edB   = align_up((size_t)E * sizeof(int2));                // 5.12 MB
    size_t w1B   = align_up((size_t)D * H * sizeof(unsigned short));  // 64 KB

    char* w = (char*)d_ws;
    unsigned short* convb    = (unsigned short*)(w);
    int*            counts   = (int*)(w + convB);
    int*            row_part = (int*)(w + convB + cntB);
    int*            cnt0     = (int*)(w + convB + cntB + rsB);
    int*            bsums    = (int*)(w + convB + cntB + rsB + c0B);
    int2*           edat     = (int2*)(w + convB + cntB + rsB + c0B + bsB);
    unsigned short* W1p      = (unsigned short*)(w + convB + cntB + rsB + c0B + bsB + edB);
    unsigned short* W2p      = (unsigned short*)(w + convB + cntB + rsB + c0B + bsB + edB + w1B);

    // 1) prep: pack weights + zero counts + zero cnt0
    int zeroBlocks = (N + 255) / 256;                // 391
    prep_kernel<<<256 + 2 * zeroBlocks, 256, 0, stream>>>(
        W1, W1p, W2, W2p, counts, cnt0, N, zeroBlocks);

    // 2) conv + hist
    int convBlocks = (N + 63) / 64;                  // 1563
    int histBlocks = (E + 255) / 256;                // 2500
    conv_hist_kernel<<<convBlocks + histBlocks, 256, 0, stream>>>(
        x, W1p, b1, g1, be1, W2p, b2, g2, be2, convb, N, eidx, counts, E, convBlocks);

    // 3) scan (2 dispatches; final add folded into fill/gather)
    int NB = (N + 1023) / 1024;   // 98
    scan1_kernel<<<NB, 256, 0, stream>>>(counts, row_part, bsums, N);
    scan2_kernel<<<1, 128, 0, stream>>>(bsums, NB);

    // 4) fill permutation (computes final offsets on the fly)
    fill_kernel<<<(E + 255) / 256, 256, 0, stream>>>(
        eidx, row_part, bsums, cnt0, edat, E);

    // 5) gather + final LN (computes segment bounds on the fly)
    gather_ln_kernel<<<(N + 3) / 4, 256, 0, stream>>>(
        x, convb, eattr, row_part, bsums, edat, g_out, b_out, out, N, E);
}

// Round 15
// 206.589 us; speedup vs baseline: 1.0328x; 1.0328x over previous
//
#include <hip/hip_runtime.h>

constexpr int D = 128;
constexpr int H = 256;
constexpr float EPS = 1e-5f;

typedef __attribute__((ext_vector_type(8))) __bf16  bf16x8;   // 4 VGPRs
typedef __attribute__((ext_vector_type(4))) float   f32x4;

static __device__ __forceinline__ unsigned short f2bfu(float f) {
    unsigned u = __float_as_uint(f);
    return (unsigned short)((u + 0x7FFFu + ((u >> 16) & 1u)) >> 16);   // RNE
}
static __device__ __forceinline__ float bf2f(unsigned short u) {
    return __uint_as_float((unsigned)u << 16);
}

static __device__ __forceinline__ f32x4 mfma16x16x32(bf16x8 a, bf16x8 b, f32x4 c) {
    return __builtin_amdgcn_mfma_f32_16x16x32_bf16(a, b, c, 0, 0, 0);
}

// ---------------------------------------------------------------------------
// Pack W element e (bf16 MFMA B-fragment order) — device helper.
// ---------------------------------------------------------------------------
static __device__ __forceinline__ void pack_w_elem(
    const float* __restrict__ W, unsigned short* __restrict__ Wp, int K, int Ncols, int e)
{
    int i  = e & 7;
    int l  = (e >> 3) & 63;
    int jt = e >> 9;
    int nt = K >> 5;
    int j  = jt / nt;
    int t  = jt - j * nt;
    int k  = 32 * t + ((l >> 4) << 3) + i;
    int c  = 16 * j + (l & 15);
    Wp[e] = f2bfu(W[(size_t)k * Ncols + c]);
}

// ---------------------------------------------------------------------------
// prep: pack W1 [0,128), pack W2 [128,256), zero counts [256,256+zb),
// zero cnt0 [256+zb, 256+2zb)
// ---------------------------------------------------------------------------
__global__ __launch_bounds__(256) void prep_kernel(
    const float* __restrict__ W1, unsigned short* __restrict__ W1p,
    const float* __restrict__ W2, unsigned short* __restrict__ W2p,
    int* __restrict__ counts, int* __restrict__ cnt0, int N, int zeroBlocks)
{
    int b = blockIdx.x;
    if (b < 128) {
        pack_w_elem(W1, W1p, D, H, b * 256 + threadIdx.x);
    } else if (b < 256) {
        pack_w_elem(W2, W2p, H, D, (b - 128) * 256 + threadIdx.x);
    } else if (b < 256 + zeroBlocks) {
        int i = (b - 256) * 256 + threadIdx.x;
        if (i < N) counts[i] = 0;
    } else {
        int i = (b - 256 - zeroBlocks) * 256 + threadIdx.x;
        if (i < N) cnt0[i] = 0;
    }
}

// ---------------------------------------------------------------------------
// Fused conv + hist (R13-verified): 64 rows/block, 4 waves x 16 rows,
// LDS-staged double-buffered weights, coalesced convb epilogue via Hs.
// ---------------------------------------------------------------------------
__global__ __launch_bounds__(256) void conv_hist_kernel(
    const float* __restrict__ x,
    const unsigned short* __restrict__ W1p, const float* __restrict__ b1,
    const float* __restrict__ g1, const float* __restrict__ be1,
    const unsigned short* __restrict__ W2p, const float* __restrict__ b2,
    const float* __restrict__ g2, const float* __restrict__ be2,
    unsigned short* __restrict__ convb, int N,
    const int* __restrict__ eidx, int* __restrict__ counts, int E, int convBlocks)
{
    __shared__ unsigned short Hs[64 * 256];   // 32 KB
    __shared__ unsigned short Ws[2][8192];    // 2 x 16 KB weight staging

    if ((int)blockIdx.x >= convBlocks) {
        int e = (blockIdx.x - convBlocks) * 256 + threadIdx.x;
        if (e < E) atomicAdd(&counts[eidx[e]], 1);
        return;
    }

    const int wv   = threadIdx.x >> 6;
    const int lane = threadIdx.x & 63;
    const int rrow = lane & 15;
    const int kgrp = lane >> 4;
    const int r0   = blockIdx.x * 64 + wv * 16;

    float4 sv0, sv1, sv2, sv3;
    auto issueW = [&](const unsigned short* Wp, int c) {
        const float4* s = (const float4*)(Wp + c * 8192);
        sv0 = s[threadIdx.x];
        sv1 = s[threadIdx.x + 256];
        sv2 = s[threadIdx.x + 512];
        sv3 = s[threadIdx.x + 768];
    };
    auto writeS = [&](int b) {
        float4* d = (float4*)Ws[b];
        d[threadIdx.x]       = sv0;
        d[threadIdx.x + 256] = sv1;
        d[threadIdx.x + 512] = sv2;
        d[threadIdx.x + 768] = sv3;
    };

    int arow = r0 + rrow; if (arow >= N) arow = N - 1;
    const float* xr = x + (size_t)arow * D + kgrp * 8;
    bf16x8 A1[4];
    #pragma unroll
    for (int t = 0; t < 4; ++t) {
        float4 fa = *(const float4*)(xr + t * 32);
        float4 fb = *(const float4*)(xr + t * 32 + 4);
        bf16x8 a;
        a[0] = (__bf16)fa.x; a[1] = (__bf16)fa.y; a[2] = (__bf16)fa.z; a[3] = (__bf16)fa.w;
        a[4] = (__bf16)fb.x; a[5] = (__bf16)fb.y; a[6] = (__bf16)fb.z; a[7] = (__bf16)fb.w;
        A1[t] = a;
    }

    f32x4 acc[16];
    #pragma unroll
    for (int j = 0; j < 16; ++j) acc[j] = (f32x4){0.f, 0.f, 0.f, 0.f};

    issueW(W1p, 0); writeS(0); __syncthreads();
    #pragma unroll
    for (int c = 0; c < 4; ++c) {
        if (c < 3) issueW(W1p, c + 1);
        #pragma unroll
        for (int jj = 0; jj < 4; ++jj) {
            #pragma unroll
            for (int t = 0; t < 4; ++t) {
                bf16x8 B = *(const bf16x8*)((const char*)Ws[c & 1]
                             + ((jj * 4 + t) * 512 + lane * 8) * 2);
                acc[c * 4 + jj] = mfma16x16x32(A1[t], B, acc[c * 4 + jj]);
            }
        }
        if (c < 3) writeS((c + 1) & 1);
        __syncthreads();
    }

    float b1r[16], g1r[16], be1r[16];
    #pragma unroll
    for (int j = 0; j < 16; ++j) {
        int c = 16 * j + rrow;
        b1r[j] = b1[c]; g1r[j] = g1[c]; be1r[j] = be1[c];
    }

    float s1[4] = {0,0,0,0}, s2[4] = {0,0,0,0};
    #pragma unroll
    for (int j = 0; j < 16; ++j) {
        #pragma unroll
        for (int r = 0; r < 4; ++r) {
            float v = acc[j][r] + b1r[j];
            acc[j][r] = v;
            s1[r] += v; s2[r] += v * v;
        }
    }
    #pragma unroll
    for (int m = 1; m < 16; m <<= 1) {
        #pragma unroll
        for (int r = 0; r < 4; ++r) {
            s1[r] += __shfl_xor(s1[r], m);
            s2[r] += __shfl_xor(s2[r], m);
        }
    }

    issueW(W2p, 0);   // overlap W2 chunk-0 loads with LN1/Hs work

    #pragma unroll
    for (int r = 0; r < 4; ++r) {
        float mu  = s1[r] * (1.f / H);
        float var = s2[r] * (1.f / H) - mu * mu;
        float rs  = rsqrtf(var + EPS);
        int row = wv * 16 + kgrp * 4 + r;
        #pragma unroll
        for (int j = 0; j < 16; ++j) {
            float h = fmaxf((acc[j][r] - mu) * rs * g1r[j] + be1r[j], 0.f);
            int byte = (row << 9) + ((16 * j + rrow) << 1);
            byte ^= (row & 15) << 4;
            *(unsigned short*)((char*)Hs + byte) = f2bfu(h);
        }
    }

    bf16x8 A2[8];
    #pragma unroll
    for (int t = 0; t < 8; ++t) {
        int row  = wv * 16 + rrow;
        int byte = (row << 9) + ((t * 32 + kgrp * 8) << 1);
        byte ^= (row & 15) << 4;
        A2[t] = *(const bf16x8*)((const char*)Hs + byte);
    }

    writeS(0); __syncthreads();

    f32x4 acc2[8];
    #pragma unroll
    for (int j = 0; j < 8; ++j) acc2[j] = (f32x4){0.f, 0.f, 0.f, 0.f};
    #pragma unroll
    for (int c = 0; c < 4; ++c) {
        if (c < 3) issueW(W2p, c + 1);
        #pragma unroll
        for (int jj = 0; jj < 2; ++jj) {
            #pragma unroll
            for (int t = 0; t < 8; ++t) {
                bf16x8 B = *(const bf16x8*)((const char*)Ws[c & 1]
                             + ((jj * 8 + t) * 512 + lane * 8) * 2);
                acc2[c * 2 + jj] = mfma16x16x32(A2[t], B, acc2[c * 2 + jj]);
            }
        }
        if (c < 3) writeS((c + 1) & 1);
        __syncthreads();
    }

    float b2r[8], g2r[8], be2r[8];
    #pragma unroll
    for (int j = 0; j < 8; ++j) {
        int c = 16 * j + rrow;
        b2r[j] = b2[c]; g2r[j] = g2[c]; be2r[j] = be2[c];
    }

    float u1[4] = {0,0,0,0}, u2[4] = {0,0,0,0};
    #pragma unroll
    for (int j = 0; j < 8; ++j) {
        #pragma unroll
        for (int r = 0; r < 4; ++r) {
            float v = acc2[j][r] + b2r[j];
            acc2[j][r] = v;
            u1[r] += v; u2[r] += v * v;
        }
    }
    #pragma unroll
    for (int m = 1; m < 16; m <<= 1) {
        #pragma unroll
        for (int r = 0; r < 4; ++r) {
            u1[r] += __shfl_xor(u1[r], m);
            u2[r] += __shfl_xor(u2[r], m);
        }
    }

    #pragma unroll
    for (int r = 0; r < 4; ++r) {
        float mu  = u1[r] * (1.f / D);
        float var = u2[r] * (1.f / D) - mu * mu;
        float rs  = rsqrtf(var + EPS);
        int row = wv * 16 + kgrp * 4 + r;
        #pragma unroll
        for (int j = 0; j < 8; ++j) {
            float o = (acc2[j][r] - mu) * rs * g2r[j] + be2r[j];
            int byte = (row << 9) + ((16 * j + rrow) << 1);
            byte ^= (row & 15) << 4;
            *(unsigned short*)((char*)Hs + byte) = f2bfu(o);
        }
    }

    // coalesced store: per k, each 4-lane group writes a dense 64B segment
    {
        int lrow = wv * 16 + (lane >> 2);
        int grow = r0 + (lane >> 2);
        if (grow < N) {
            #pragma unroll
            for (int k = 0; k < 4; ++k) {
                int chunk = k * 4 + (lane & 3);
                int byte  = (lrow << 9) + (chunk << 4);
                byte ^= (lrow & 15) << 4;
                uint4 v = *(const uint4*)((const char*)Hs + byte);
                *(uint4*)(convb + (size_t)grow * D + chunk * 8) = v;
            }
        }
    }
}

// ---------------------------------------------------------------------------
// scan1: per-1024-block exclusive partials -> row_part, block totals -> bsums
// scan2: exclusive scan of bsums in place.  (scan3 folded into consumers)
// ---------------------------------------------------------------------------
__global__ __launch_bounds__(256) void scan1_kernel(
    const int* __restrict__ counts, int* __restrict__ row_part,
    int* __restrict__ bsums, int N)
{
    __shared__ int sd[256];
    int t  = threadIdx.x;
    int i0 = blockIdx.x * 1024 + t * 4;
    int c0 = (i0+0 < N) ? counts[i0+0] : 0;
    int c1 = (i0+1 < N) ? counts[i0+1] : 0;
    int c2 = (i0+2 < N) ? counts[i0+2] : 0;
    int c3 = (i0+3 < N) ? counts[i0+3] : 0;
    int s  = c0 + c1 + c2 + c3;
    sd[t] = s;
    __syncthreads();
    #pragma unroll
    for (int off = 1; off < 256; off <<= 1) {
        int v = (t >= off) ? sd[t - off] : 0;
        __syncthreads();
        sd[t] += v;
        __syncthreads();
    }
    int ex = sd[t] - s;
    if (i0+0 < N) row_part[i0+0] = ex;
    if (i0+1 < N) row_part[i0+1] = ex + c0;
    if (i0+2 < N) row_part[i0+2] = ex + c0 + c1;
    if (i0+3 < N) row_part[i0+3] = ex + c0 + c1 + c2;
    if (t == 255) bsums[blockIdx.x] = sd[255];
}

__global__ __launch_bounds__(128) void scan2_kernel(int* __restrict__ bsums, int NB)
{
    __shared__ int sd[128];
    int t = threadIdx.x;
    int v = (t < NB) ? bsums[t] : 0;
    sd[t] = v;
    __syncthreads();
    #pragma unroll
    for (int off = 1; off < 128; off <<= 1) {
        int u = (t >= off) ? sd[t - off] : 0;
        __syncthreads();
        sd[t] += u;
        __syncthreads();
    }
    if (t < NB) bsums[t] = sd[t] - v;
}

// ---------------------------------------------------------------------------
// fill: p = row_part[src] + bsums[src>>10] + cnt0[src]++  ;  edat[p]={e,dst}
// ---------------------------------------------------------------------------
__global__ __launch_bounds__(256) void fill_kernel(
    const int* __restrict__ eidx,
    const int* __restrict__ row_part, const int* __restrict__ bsums,
    int* __restrict__ cnt0, int2* __restrict__ edat, int E)
{
    int e = blockIdx.x * blockDim.x + threadIdx.x;
    if (e < E) {
        int s    = eidx[e];
        int base = row_part[s] + bsums[s >> 10];
        int p    = base + atomicAdd(&cnt0[s], 1);
        edat[p]  = make_int2(e, eidx[E + e]);
    }
}

// ---------------------------------------------------------------------------
// out[v] = LN( x[v] + sum_{e: src=v} conv_bf16[dst]*eattr[e] )
// Persistent-wave grid-stride: each wave owns nodes {id, id+W, id+2W, ...}
// -> wave-retirement skew from degree variance amortized over ~12 nodes.
// ---------------------------------------------------------------------------
__global__ __launch_bounds__(256) void gather_ln_kernel(
    const float* __restrict__ x, const unsigned short* __restrict__ convb,
    const float* __restrict__ eattr,
    const int* __restrict__ row_part, const int* __restrict__ bsums,
    const int2* __restrict__ edat,
    const float* __restrict__ g, const float* __restrict__ b,
    float* __restrict__ out, int N, int E, int totalWaves)
{
    int waveId = blockIdx.x * 4 + (threadIdx.x >> 6);
    int lane = threadIdx.x & 63;
    int half = lane >> 5;
    int c4   = (lane & 31) * 4;

    float4 gv = *(const float4*)(g + c4);
    float4 bv = *(const float4*)(b + c4);

    for (int node = waveId; node < N; node += totalWaves) {
        int jb = row_part[node] + bsums[node >> 10];
        int je = (node + 1 < N) ? (row_part[node + 1] + bsums[(node + 1) >> 10]) : E;

        // issue x load early so it overlaps the edge stream
        float4 xv = make_float4(0.f, 0.f, 0.f, 0.f);
        if (half == 0) xv = *(const float4*)(x + (size_t)node * D + c4);

        float4 acc = make_float4(0.f, 0.f, 0.f, 0.f);
        int j = jb + half;

        for (; j + 2 < je; j += 4) {
            int2 ea = edat[j];
            int2 eb = edat[j + 2];
            ushort4 ca = *(const ushort4*)(convb + (size_t)ea.y * D + c4);
            float4  aa = *(const float4*) (eattr + (size_t)ea.x * D + c4);
            ushort4 cb = *(const ushort4*)(convb + (size_t)eb.y * D + c4);
            float4  ab = *(const float4*) (eattr + (size_t)eb.x * D + c4);
            acc.x += bf2f(ca.x) * aa.x; acc.y += bf2f(ca.y) * aa.y;
            acc.z += bf2f(ca.z) * aa.z; acc.w += bf2f(ca.w) * aa.w;
            acc.x += bf2f(cb.x) * ab.x; acc.y += bf2f(cb.y) * ab.y;
            acc.z += bf2f(cb.z) * ab.z; acc.w += bf2f(cb.w) * ab.w;
        }
        if (j < je) {
            int2 ea = edat[j];
            ushort4 ca = *(const ushort4*)(convb + (size_t)ea.y * D + c4);
            float4  aa = *(const float4*) (eattr + (size_t)ea.x * D + c4);
            acc.x += bf2f(ca.x) * aa.x; acc.y += bf2f(ca.y) * aa.y;
            acc.z += bf2f(ca.z) * aa.z; acc.w += bf2f(ca.w) * aa.w;
        }

        acc.x += xv.x; acc.y += xv.y; acc.z += xv.z; acc.w += xv.w;

        acc.x += __shfl_xor(acc.x, 32);
        acc.y += __shfl_xor(acc.y, 32);
        acc.z += __shfl_xor(acc.z, 32);
        acc.w += __shfl_xor(acc.w, 32);

        float s1 = acc.x + acc.y + acc.z + acc.w;
        float s2 = acc.x*acc.x + acc.y*acc.y + acc.z*acc.z + acc.w*acc.w;
        #pragma unroll
        for (int o = 1; o < 32; o <<= 1) {
            s1 += __shfl_xor(s1, o);
            s2 += __shfl_xor(s2, o);
        }
        float mu  = s1 * (1.f / D);
        float var = s2 * (1.f / D) - mu * mu;
        float rs  = rsqrtf(var + EPS);
        if (half == 0) {
            float4 o4;
            o4.x = (acc.x - mu) * rs * gv.x + bv.x;
            o4.y = (acc.y - mu) * rs * gv.y + bv.y;
            o4.z = (acc.z - mu) * rs * gv.z + bv.z;
            o4.w = (acc.w - mu) * rs * gv.w + bv.w;
            *(float4*)(out + (size_t)node * D + c4) = o4;
        }
    }
}

extern "C" void kernel_launch(void* const* d_in, const int* in_sizes, int n_in,
                              void* d_out, int out_size, void* d_ws, size_t ws_size,
                              hipStream_t stream) {
    const float* x     = (const float*)d_in[0];
    const int*   eidx  = (const int*)  d_in[1];
    const float* eattr = (const float*)d_in[2];
    const float* W1    = (const float*)d_in[3];
    const float* b1    = (const float*)d_in[4];
    const float* g1    = (const float*)d_in[5];
    const float* be1   = (const float*)d_in[6];
    const float* W2    = (const float*)d_in[7];
    const float* b2    = (const float*)d_in[8];
    const float* g2    = (const float*)d_in[9];
    const float* be2   = (const float*)d_in[10];
    const float* g_out = (const float*)d_in[11];
    const float* b_out = (const float*)d_in[12];

    const int N = in_sizes[0] / D;   // 100000
    const int E = in_sizes[1] / 2;   // 640000

    float* out = (float*)d_out;

    // workspace layout (256B aligned)
    auto align_up = [](size_t v) { return (v + 255) & ~(size_t)255; };
    size_t convB = align_up((size_t)N * D * sizeof(unsigned short));  // 25.6 MB
    size_t cntB  = align_up((size_t)N * sizeof(int));
    size_t rsB   = align_up((size_t)N * sizeof(int));
    size_t c0B   = align_up((size_t)N * sizeof(int));
    size_t bsB   = align_up(128 * sizeof(int));
    size_t edB   = align_up((size_t)E * sizeof(int2));                // 5.12 MB
    size_t w1B   = align_up((size_t)D * H * sizeof(unsigned short));  // 64 KB

    char* w = (char*)d_ws;
    unsigned short* convb    = (unsigned short*)(w);
    int*            counts   = (int*)(w + convB);
    int*            row_part = (int*)(w + convB + cntB);
    int*            cnt0     = (int*)(w + convB + cntB + rsB);
    int*            bsums    = (int*)(w + convB + cntB + rsB + c0B);
    int2*           edat     = (int2*)(w + convB + cntB + rsB + c0B + bsB);
    unsigned short* W1p      = (unsigned short*)(w + convB + cntB + rsB + c0B + bsB + edB);
    unsigned short* W2p      = (unsigned short*)(w + convB + cntB + rsB + c0B + bsB + edB + w1B);

    // 1) prep: pack weights + zero counts + zero cnt0
    int zeroBlocks = (N + 255) / 256;                // 391
    prep_kernel<<<256 + 2 * zeroBlocks, 256, 0, stream>>>(
        W1, W1p, W2, W2p, counts, cnt0, N, zeroBlocks);

    // 2) conv + hist
    int convBlocks = (N + 63) / 64;                  // 1563
    int histBlocks = (E + 255) / 256;                // 2500
    conv_hist_kernel<<<convBlocks + histBlocks, 256, 0, stream>>>(
        x, W1p, b1, g1, be1, W2p, b2, g2, be2, convb, N, eidx, counts, E, convBlocks);

    // 3) scan (2 dispatches; final add folded into fill/gather)
    int NB = (N + 1023) / 1024;   // 98
    scan1_kernel<<<NB, 256, 0, stream>>>(counts, row_part, bsums, N);
    scan2_kernel<<<1, 128, 0, stream>>>(bsums, NB);

    // 4) fill permutation
    fill_kernel<<<(E + 255) / 256, 256, 0, stream>>>(
        eidx, row_part, bsums, cnt0, edat, E);

    // 5) gather + final LN — persistent waves (2048 blocks = 8192 waves,
    //    all co-resident; each wave grid-strides ~12 nodes -> skew amortized)
    int gBlocks = 2048;
    int totalWaves = gBlocks * 4;
    gather_ln_kernel<<<gBlocks, 256, 0, stream>>>(
        x, convb, eattr, row_part, bsums, edat, g_out, b_out, out, N, E, totalWaves);
}